// Round 3
// baseline (406.042 us; speedup 1.0000x reference)
//
#include <hip/hip_runtime.h>

// LIF scan: x[B,T,N] f32 -> spikes[B,T,N] f32
//   v = v + (x - v)/2 ; s = (v >= 1) ; v = s ? 0 : v
// Sequential in t only; B*N independent chains. Memory-bound streaming
// (~420 MB total traffic -> ~70 us floor at 6.3 TB/s).
//
// R1: 337 us at 4 waves/CU (float4, 256 blocks) -- latency-bound, ~1 load
// in flight. Fix: float2 chains (512 blocks -> 8 waves/CU) + explicit
// depth-8 rotating prefetch buffer so ~8 loads stay in flight per wave.
// R2: __builtin_nontemporal_* needs a Clang ext-vector, not HIP float2.

typedef float vfloat2 __attribute__((ext_vector_type(2)));

constexpr int B = 64;
constexpr int T = 200;
constexpr int N = 4096;
constexpr int N2 = N / 2;   // 2048 float2 per (b,t) row
constexpr int PF = 8;       // prefetch depth (T=200 is a multiple of PF)

__global__ __launch_bounds__(256) void lif_kernel(const vfloat2* __restrict__ x,
                                                  vfloat2* __restrict__ out) {
    const int idx = blockIdx.x * blockDim.x + threadIdx.x;  // 0 .. B*N2-1
    const int b = idx >> 11;          // idx / N2
    const int n = idx & (N2 - 1);     // idx % N2

    const vfloat2* __restrict__ xp = x + (size_t)b * (T * N2) + n;
    vfloat2* __restrict__ op = out + (size_t)b * (T * N2) + n;

    vfloat2 buf[PF];
#pragma unroll
    for (int j = 0; j < PF; ++j) {
        buf[j] = __builtin_nontemporal_load(&xp[j * N2]);
    }

    vfloat2 v = {0.0f, 0.0f};

    for (int t = 0; t < T; t += PF) {
#pragma unroll
        for (int j = 0; j < PF; ++j) {
            const vfloat2 xv = buf[j];         // waits on the load from 8 steps ago
            const int tn = t + j + PF;
            if (tn < T) {                      // wave-uniform branch
                buf[j] = __builtin_nontemporal_load(&xp[tn * N2]);
            }

            // v = v + (x - v) * 0.5f  -- *0.5 exact; bit-identical to the
            // f32 numpy reference with or without fma contraction.
            v.x = v.x + (xv.x - v.x) * 0.5f;
            v.y = v.y + (xv.y - v.y) * 0.5f;

            vfloat2 s;
            s.x = (v.x >= 1.0f) ? 1.0f : 0.0f;
            s.y = (v.y >= 1.0f) ? 1.0f : 0.0f;
            v.x = (v.x >= 1.0f) ? 0.0f : v.x;
            v.y = (v.y >= 1.0f) ? 0.0f : v.y;

            __builtin_nontemporal_store(s, &op[(t + j) * N2]);
        }
    }
}

extern "C" void kernel_launch(void* const* d_in, const int* in_sizes, int n_in,
                              void* d_out, int out_size, void* d_ws, size_t ws_size,
                              hipStream_t stream) {
    const vfloat2* x = (const vfloat2*)d_in[0];  // [B,T,N] f32
    // d_in[1] (threshold, 1xN) is unused by the reference math.
    vfloat2* out = (vfloat2*)d_out;

    const int threads = B * N2;         // 131072 float2 chains
    const int block = 256;
    const int grid = threads / block;   // 512 blocks -> 2 blocks/CU, 8 waves/CU
    lif_kernel<<<grid, block, 0, stream>>>(x, out);
}

// Round 4
// 342.643 us; speedup vs baseline: 1.1850x; 1.1850x over previous
//
#include <hip/hip_runtime.h>

// LIF scan: x[B,T,N] f32 -> spikes[B,T,N] f32
//   v = v + (x - v)/2 ; s = (v >= 1) ; v = s ? 0 : v
// Sequential in t only; B*N independent chains. Memory-bound streaming.
// HBM traffic ~315 MB (write 210 MB + fetch ~105 MB; LLC holds half the
// input thanks to the harness restore-write) -> floor ~55-70 us.
//
// R1: float4, 256 blocks (4 waves/CU), plain unroll-8 -> kernel <=127 us.
// R3: float2 + manual rotating prefetch + nt + per-iter branch -> 151 us,
//     2.08 TB/s. REGRESSION: hand pipeline kept only ~3 KB/CU in flight;
//     the compiler's own scheduling of a branch-free unrolled body is better.
// R4: R1 structure (compiler-scheduled loads, no nt, branch-free body),
//     float2 width -> 512 blocks = 8 waves/CU, 2x latency hiding at the
//     same 32 KB/CU bytes-in-flight.

typedef float vfloat2 __attribute__((ext_vector_type(2)));

constexpr int B = 64;
constexpr int T = 200;
constexpr int N = 4096;
constexpr int N2 = N / 2;   // 2048 float2 per (b,t) row

__global__ __launch_bounds__(256) void lif_kernel(const vfloat2* __restrict__ x,
                                                  vfloat2* __restrict__ out) {
    const int idx = blockIdx.x * blockDim.x + threadIdx.x;  // 0 .. B*N2-1
    const int b = idx >> 11;          // idx / N2
    const int n = idx & (N2 - 1);     // idx % N2

    const vfloat2* __restrict__ xp = x + (size_t)b * (T * N2) + n;
    vfloat2* __restrict__ op = out + (size_t)b * (T * N2) + n;

    vfloat2 v = {0.0f, 0.0f};

    // T = 200 = 8 * 25: branch-free unrolled body; the 8 loads are
    // independent of the serial v-chain, so the compiler hoists and
    // clusters them (this is what made R1 fast).
#pragma unroll 8
    for (int t = 0; t < T; ++t) {
        const vfloat2 xv = xp[t * N2];

        // v = v + (x - v) * 0.5f  -- *0.5 exact; bit-identical to the
        // f32 numpy reference with or without fma contraction.
        v.x = v.x + (xv.x - v.x) * 0.5f;
        v.y = v.y + (xv.y - v.y) * 0.5f;

        vfloat2 s;
        s.x = (v.x >= 1.0f) ? 1.0f : 0.0f;
        s.y = (v.y >= 1.0f) ? 1.0f : 0.0f;
        v.x = (v.x >= 1.0f) ? 0.0f : v.x;
        v.y = (v.y >= 1.0f) ? 0.0f : v.y;

        op[t * N2] = s;
    }
}

extern "C" void kernel_launch(void* const* d_in, const int* in_sizes, int n_in,
                              void* d_out, int out_size, void* d_ws, size_t ws_size,
                              hipStream_t stream) {
    const vfloat2* x = (const vfloat2*)d_in[0];  // [B,T,N] f32
    // d_in[1] (threshold, 1xN) is unused by the reference math.
    vfloat2* out = (vfloat2*)d_out;

    const int threads = B * N2;         // 131072 float2 chains
    const int block = 256;
    const int grid = threads / block;   // 512 blocks -> 2 blocks/CU, 8 waves/CU
    lif_kernel<<<grid, block, 0, stream>>>(x, out);
}